// Round 13
// baseline (282.450 us; speedup 1.0000x reference)
//
#include <hip/hip_runtime.h>
#include <math.h>

// Problem constants
#define T_SEQ 2048
#define CDIM  1024
#define NH    16
#define DHD   64
#define BATCH 4
#define MROWS (BATCH * T_SEQ)   // 8192
#define BHN   (BATCH * NH)      // 64

typedef _Float16 f16;
typedef __attribute__((ext_vector_type(8))) _Float16 f16x8;
typedef __attribute__((ext_vector_type(4))) _Float16 f16x4;
typedef __attribute__((ext_vector_type(2))) _Float16 f16x2;
typedef __attribute__((ext_vector_type(2))) __fp16 fp16x2;
typedef __attribute__((ext_vector_type(4))) float f32x4;
typedef __attribute__((ext_vector_type(16))) float f32x16;
typedef __attribute__((ext_vector_type(4))) unsigned int uint4v;

__device__ __forceinline__ float fast_exp2(float x) {
#if __has_builtin(__builtin_amdgcn_exp2f)
    return __builtin_amdgcn_exp2f(x);
#else
    return exp2f(x);
#endif
}

__device__ __forceinline__ float fast_rcp(float x) {
#if __has_builtin(__builtin_amdgcn_rcpf)
    return __builtin_amdgcn_rcpf(x);
#else
    return 1.0f / x;
#endif
}

// packed f32x2 -> f16x2 convert (v_cvt_pkrtz_f16_f32)
__device__ __forceinline__ f16x2 cvt_pk_f16(float a, float b) {
    fp16x2 r = __builtin_amdgcn_cvt_pkrtz(a, b);
    return __builtin_bit_cast(f16x2, r);
}

// v_permlane32_swap_b32: positional 32-lane half exchange
__device__ __forceinline__ void permlane32_swap(unsigned &a, unsigned &b) {
    asm volatile("v_permlane32_swap_b32 %0, %1" : "+v"(a), "+v"(b));
}

// async global->LDS, 16B per lane; LDS dest = wave-uniform base + lane*16
__device__ __forceinline__ void gl_lds16(const f16* g, f16* l) {
    __builtin_amdgcn_global_load_lds(
        (const __attribute__((address_space(1))) void*)(g),
        (__attribute__((address_space(3))) void*)(l),
        16, 0, 0);
}

// ---------------------------------------------------------------------------
// Prep kernel (one launch): RoPE tables + X fp32->f16 + both W transposes
// ---------------------------------------------------------------------------
__global__ __launch_bounds__(256) void prep_kernel(
    const float* __restrict__ X, f16* __restrict__ Xf,
    const float* __restrict__ Wq, const float* __restrict__ Wo,
    f16* __restrict__ Wqt, f16* __restrict__ Wot,
    float* __restrict__ ctab, float* __restrict__ stab)
{
    const int bx = blockIdx.x;
    if (bx < 256) {
        int idx = bx * 256 + threadIdx.x;   // 0 .. 2048*32-1
        int t = idx >> 5, i = idx & 31;
        double inv = pow(10000.0, -(double)(2 * i) / 64.0);
        double a = (double)t * inv;
        ctab[idx] = (float)cos(a);
        stab[idx] = (float)sin(a);
    } else if (bx < 4352) {
        int idx = (bx - 256) * 256 + threadIdx.x;   // 8-elem chunk index
        const float4* src = (const float4*)X + (size_t)idx * 2;
        float4 a = src[0], b = src[1];
        f16x8 o;
        o[0] = (f16)a.x; o[1] = (f16)a.y; o[2] = (f16)a.z; o[3] = (f16)a.w;
        o[4] = (f16)b.x; o[5] = (f16)b.y; o[6] = (f16)b.z; o[7] = (f16)b.w;
        *((f16x8*)Xf + idx) = o;
    } else {
        const int sub = threadIdx.x >> 6, lane = threadIdx.x & 63;
        const int id = (bx - 4352) * 4 + sub;   // 0..8191
        const int k0 = (id & 127) * 8;
        const int ny = id >> 7;                 // 0..63
        const float* W;
        f16* Wt;
        int N, n;
        if (ny < 48) { W = Wq; Wt = Wqt; N = 3072; n = ny * 64 + lane; }
        else         { W = Wo; Wt = Wot; N = 1024; n = (ny - 48) * 64 + lane; }
        f16x8 o;
#pragma unroll
        for (int j = 0; j < 8; j++) o[j] = (f16)W[(size_t)(k0 + j) * N + n];
        *(f16x8*)(Wt + (size_t)n * CDIM + k0) = o;
    }
}

// ---------------------------------------------------------------------------
// f16 MFMA GEMM mainloop (128x128, 2-barrier, BK=64, XOR-swizzled) —
// the R5-proven structure; used by BOTH qkv and out_gemm.
// ---------------------------------------------------------------------------
#define GEMM_MAINLOOP(Aimg, Bimg, M0, N0)                                         \
    __shared__ f16 As[128][64], Bs[128][64];                                      \
    const int tid = threadIdx.x, wave = tid >> 6, lane = tid & 63;                \
    const int l16 = lane & 15, quad = lane >> 4;                                  \
    const int wm = wave >> 1, wn = wave & 1;                                      \
    f32x4 acc[4][4];                                                              \
    _Pragma("unroll") for (int i = 0; i < 4; i++)                                 \
        _Pragma("unroll") for (int j = 0; j < 4; j++)                             \
            acc[i][j] = (f32x4){0.f, 0.f, 0.f, 0.f};                              \
    const f16* sbase = (wave < 2) ? (Aimg) : (Bimg);                              \
    f16* lbase = ((wave < 2) ? &As[0][0] : &Bs[0][0]) + (wave & 1) * 4096;        \
    const size_t srow0 = ((wave < 2) ? (size_t)(M0) : (size_t)(N0)) + (wave & 1) * 64; \
    const int srow = lane >> 3, schunk = lane & 7;                                \
    const int gchunk = (schunk ^ srow) << 3;   /* pre-swizzled global col */      \
    for (int k0 = 0; k0 < CDIM; k0 += 64) {                                       \
        _Pragma("unroll") for (int it = 0; it < 8; it++)                          \
            gl_lds16(sbase + (srow0 + it * 8 + srow) * CDIM + k0 + gchunk,        \
                     lbase + it * 512);                                           \
        __syncthreads();                                                          \
        _Pragma("unroll") for (int ks = 0; ks < 2; ks++) {                        \
            f16x8 fa[4], fb[4];                                                   \
            _Pragma("unroll") for (int mi = 0; mi < 4; mi++)                      \
                fa[mi] = *(const f16x8*)                                          \
                    &As[wm * 64 + mi * 16 + l16][((ks * 4 + quad) ^ (l16 & 7)) << 3]; \
            _Pragma("unroll") for (int ni = 0; ni < 4; ni++)                      \
                fb[ni] = *(const f16x8*)                                          \
                    &Bs[wn * 64 + ni * 16 + l16][((ks * 4 + quad) ^ (l16 & 7)) << 3]; \
            _Pragma("unroll") for (int mi = 0; mi < 4; mi++)                      \
                _Pragma("unroll") for (int ni = 0; ni < 4; ni++)                  \
                    acc[mi][ni] = __builtin_amdgcn_mfma_f32_16x16x32_f16(         \
                        fa[mi], fb[ni], acc[mi][ni], 0, 0, 0);                    \
        }                                                                         \
        __syncthreads();                                                          \
    }

// ---------------------------------------------------------------------------
// QKV GEMM — 128x128 R5 structure + permuted-RoPE vectorized epilogue.
//  - XCD-chunked grid swizzle: each XCD owns an 8-mblk x 24-nblk subgrid ->
//    its X panels (2MB) stay L2-resident; W streams once per XCD
//  - PERMUTED RoPE layout: rotate-half pair (d, d+32) stored at physical
//    (2d, 2d+1) as ONE f16x2 (QK^T invariant; refcheck'd R10-R12)
//  - V stored directly transposed into vt[bh][d][t].
// ---------------------------------------------------------------------------
__global__ __launch_bounds__(256) void qkv_gemm_kernel(
    const f16* __restrict__ Xf, const f16* __restrict__ Wt,
    const float* __restrict__ bias,
    const float* __restrict__ ctab, const float* __restrict__ stab,
    f16* __restrict__ qf, f16* __restrict__ kf, f16* __restrict__ vtb)
{
    // XCD swizzle: flat 0..1535; xcd = flat&7; idx = flat>>3 (0..191)
    // -> mblk = xcd*8 + (idx&7) in 0..63, nblk = idx>>3 in 0..23 (bijective)
    const int flat = blockIdx.x + (blockIdx.y << 6);
    const int idx  = flat >> 3;
    const int m0 = ((flat & 7) * 8 + (idx & 7)) * 128;
    const int n0 = (idx >> 3) * 128;
    GEMM_MAINLOOP(Xf, Wt, m0, n0)

    const int ncol0 = n0 + wn * 64;            // 64-aligned -> one head group
    const int w = ncol0 >> 10;                 // 0=q 1=k 2=v
    const int h = (ncol0 >> 6) & 15;
    const int b = m0 >> 11;
    const int trow0 = (m0 & 2047) + wm * 64 + quad * 4;
    float bia[4];
#pragma unroll
    for (int ni = 0; ni < 4; ni++) bia[ni] = bias[ncol0 + ni * 16 + l16];

    if (w < 2) {
        f16* oq = w ? kf : qf;
        // q scale folds softmax 1/8 AND log2(e) so attn can use v_exp (2^x)
        const float sc = w ? 1.0f : 0.18033688011112042f;
#pragma unroll
        for (int mi = 0; mi < 4; mi++) {
#pragma unroll
            for (int i = 0; i < 4; i++) {
                int t = trow0 + mi * 16 + i;
                size_t rowoff = ((size_t)(b * NH + h) * T_SEQ + t) * DHD;
#pragma unroll
                for (int np = 0; np < 2; np++) {
                    int d = np * 16 + l16;             // logical 0..31
                    float v0 = acc[mi][np][i] + bia[np];
                    float v1 = acc[mi][np + 2][i] + bia[np + 2];
                    float c = ctab[(t << 5) + d];
                    float s = stab[(t << 5) + d];
                    // permuted layout: logical (d, d+32) at physical (2d, 2d+1)
                    f16x2 pr;
                    pr[0] = (f16)((v0 * c - v1 * s) * sc);
                    pr[1] = (f16)((v1 * c + v0 * s) * sc);
                    *(f16x2*)(oq + rowoff + 2 * d) = pr;
                }
            }
        }
    } else {
#pragma unroll
        for (int mi = 0; mi < 4; mi++) {
            const int tb = trow0 + mi * 16;    // includes quad*4; 4-aligned
#pragma unroll
            for (int ni = 0; ni < 4; ni++) {
                const int d = ni * 16 + l16;
                f16x4 pv;
#pragma unroll
                for (int i = 0; i < 4; i++) pv[i] = (f16)(acc[mi][ni][i] + bia[ni]);
                *(f16x4*)(vtb + ((size_t)(b * NH + h) * DHD + d) * T_SEQ + tb) = pv;
            }
        }
    }
}

// ---------------------------------------------------------------------------
// f16 MFMA flash attention v10 — R12 structure + MFMA l-accumulation:
//  - l via mfma_32x32x16(pA, ones, lacc16): replaces the 32-deep SERIAL
//    dependent VALU add chain per tile (critical pipe, 52% busy) with 4
//    MFMAs on the 38%-busy pipe. l lands in the SAME C-layout as o ->
//    epilogue 1/l is lane-local: shfl_xor, Lb, and final barrier removed.
//  - otherwise the measured-best structure: 32x32 MFMA, register-only P
//    via permlane32_swap, gl_lds staging, XCD-chunked block swizzle
// ---------------------------------------------------------------------------
__global__ __launch_bounds__(256, 4) void attn_kernel(
    const f16* __restrict__ qf, const f16* __restrict__ kf,
    const f16* __restrict__ vt, f16* __restrict__ ab)
{
    __shared__ f16 Kb[2][64][64];     // [buf][key][d]   16384B, chunk-swizzled
    __shared__ f16 Vb[2][64][64];     // [buf][d][key]   16384B, chunk-swizzled

    const int tid  = threadIdx.x;
    const int wave = tid >> 6, lane = tid & 63;
    const int l31  = lane & 31, hh = lane >> 5;

    // XCD-chunked swizzle: flat id -> (qt, bh) so XCD x holds bh in [8x, 8x+8)
    const int flat = blockIdx.x + (blockIdx.y << 4);     // 0..1023
    const int swz  = (flat & 7) * 128 + (flat >> 3);     // bijective (1024%8==0)
    const int qt = swz & 15;                             // 0..15
    const int bh = swz >> 4;                             // 0..63
    const int q0 = qt * 128 + wave * 32;                 // wave's query base

    const f16* kbase = kf + (size_t)bh * T_SEQ * DHD;
    const f16* vbase = vt + (size_t)bh * DHD * T_SEQ;

    // Q B-frags: qfr[kk] = Q[query=q0+l31][d = kk*16 + hh*8 .. +7]
    f16x8 qfr[4];
    {
        const f16* qrow = qf + ((size_t)bh * T_SEQ + q0 + l31) * DHD + hh * 8;
#pragma unroll
        for (int kk = 0; kk < 4; kk++)
            qfr[kk] = *(const f16x8*)(qrow + kk * 16);
    }

    f32x16 o[2];        // [dblk]: C row=query=(r&3)+8*(r>>2)+4*hh, col=d=dblk*32+l31
#pragma unroll
    for (int db = 0; db < 2; db++)
#pragma unroll
        for (int r = 0; r < 16; r++) o[db][r] = 0.f;
    f32x16 lacc16;      // l in the SAME C-layout (row=query, col identical)
#pragma unroll
    for (int r = 0; r < 16; r++) lacc16[r] = 0.f;

    // never-modified zero accumulator: C-input of the first QK^T MFMA
    f32x16 zero16;
#pragma unroll
    for (int r = 0; r < 16; r++) zero16[r] = 0.f;

    // all-ones B fragment for MFMA l-accumulation
    f16x8 ones;
#pragma unroll
    for (int j = 0; j < 8; j++) ones[j] = (f16)1.0f;

    // staging map (gl_lds): thread -> row srow(+32), phys chunk schunk;
    // global col pre-XORed so phys chunk p of row r = global chunk p^(r&7)
    const int srow = tid >> 3;                       // 0..31
    const int schunk = tid & 7;
    const int gcol = (schunk ^ (srow & 7)) << 3;

    // incremental per-lane staging pointers
    const f16* kg = kbase + (size_t)srow * DHD + gcol;
    const f16* vg = vbase + (size_t)srow * T_SEQ + gcol;

    {   // stage tile 0 into buf 0
        f16* kl = &Kb[0][wave * 8][0];
        f16* vl = &Vb[0][wave * 8][0];
        gl_lds16(kg, kl);
        gl_lds16(kg + 32 * DHD, kl + 32 * 64);
        gl_lds16(vg, vl);
        gl_lds16(vg + (size_t)32 * T_SEQ, vl + 32 * 64);
        kg += 64 * DHD;
        vg += 64;
    }
    __syncthreads();

    for (int kt = 0; kt < 32; kt++) {
        const int buf = kt & 1;
        if (kt < 31) {   // stage next tile into the other buffer
            f16* kl = &Kb[buf ^ 1][wave * 8][0];
            f16* vl = &Vb[buf ^ 1][wave * 8][0];
            gl_lds16(kg, kl);
            gl_lds16(kg + 32 * DHD, kl + 32 * 64);
            gl_lds16(vg, vl);
            gl_lds16(vg + (size_t)32 * T_SEQ, vl + 32 * 64);
            kg += 64 * DHD;
            vg += 64;
        }

        f16x8 pA[4];    // PV A-frags, keys kk*16 + hh*8 + j of query l31
#pragma unroll
        for (int b2 = 0; b2 < 2; b2++) {
            // ---- S^T for 32-key block b2 x 32 queries ----
            f32x16 scc;
            __builtin_amdgcn_s_setprio(1);
#pragma unroll
            for (int kk = 0; kk < 4; kk++) {
                const int kc = ((kk * 2 + hh) ^ (l31 & 7)) << 3;
                f16x8 kfr = *(const f16x8*)&Kb[buf][b2 * 32 + l31][kc];
                scc = __builtin_amdgcn_mfma_f32_32x32x16_f16(
                    kfr, qfr[kk], kk == 0 ? zero16 : scc, 0, 0, 0);
            }
            __builtin_amdgcn_s_setprio(0);
            // ---- exp2 + pack (NO serial l chain: l comes from MFMA) ----
            float e[16];
#pragma unroll
            for (int r = 0; r < 16; r++) e[r] = fast_exp2(scc[r]);
            unsigned pk[8];
#pragma unroll
            for (int i = 0; i < 8; i++)
                pk[i] = __builtin_bit_cast(unsigned,
                                           cvt_pk_f16(e[2 * i], e[2 * i + 1]));
            // ---- half-exchange: pk -> A-frag dwords ----
            permlane32_swap(pk[0], pk[2]);
            permlane32_swap(pk[1], pk[3]);
            permlane32_swap(pk[4], pk[6]);
            permlane32_swap(pk[5], pk[7]);
            uint4v a0 = {pk[0], pk[1], pk[2], pk[3]};
            uint4v a1 = {pk[4], pk[5], pk[6], pk[7]};
            pA[b2 * 2]     = __builtin_bit_cast(f16x8, a0);
            pA[b2 * 2 + 1] = __builtin_bit_cast(f16x8, a1);
        }
        // ---- l += P*ones and PV, all on the MFMA pipe ----
        __builtin_amdgcn_s_setprio(1);
#pragma unroll
        for (int kk = 0; kk < 4; kk++)
            lacc16 = __builtin_amdgcn_mfma_f32_32x32x16_f16(
                pA[kk], ones, lacc16, 0, 0, 0);
#pragma unroll
        for (int db = 0; db < 2; db++) {
#pragma unroll
            for (int kk = 0; kk < 4; kk++) {
                const int vc = ((kk * 2 + hh) ^ (l31 & 7)) << 3;
                f16x8 vfr = *(const f16x8*)&Vb[buf][db * 32 + l31][vc];
                o[db] = __builtin_amdgcn_mfma_f32_32x32x16_f16(
                    pA[kk], vfr, o[db], 0, 0, 0);
            }
        }
        __builtin_amdgcn_s_setprio(0);

        if (kt < 31) __syncthreads();
    }

    // ---- epilogue: 1/l is lane-local (same C-layout as o) ----
    const int b = bh >> 4, h = bh & 15;
#pragma unroll
    for (int r = 0; r < 16; r++) {
        const int qrow = (r & 3) + 8 * (r >> 2) + 4 * hh;
        const int m = b * T_SEQ + qt * 128 + wave * 32 + qrow;
        const float iv = fast_rcp(lacc16[r]);
        f16* dst = ab + (size_t)m * CDIM + h * 64 + l31;
        dst[0]  = (f16)(o[0][r] * iv);
        dst[32] = (f16)(o[1][r] * iv);
    }
}

// ---------------------------------------------------------------------------
// Output GEMM (f16 MFMA): out = ab @ Wout + bias (fp32 out)
//  - XCD-chunked grid swizzle (same scheme as qkv)
// ---------------------------------------------------------------------------
__global__ __launch_bounds__(256) void out_gemm_kernel(
    const f16* __restrict__ Ab, const f16* __restrict__ Wt,
    const float* __restrict__ bias, float* __restrict__ out)
{
    // flat 0..511; xcd = flat&7; idx = flat>>3 (0..63)
    // -> mblk = xcd*8 + (idx&7) in 0..63, nblk = idx>>3 in 0..7 (bijective)
    const int flat = blockIdx.x + (blockIdx.y << 6);
    const int idx  = flat >> 3;
    const int m0 = ((flat & 7) * 8 + (idx & 7)) * 128;
    const int n0 = (idx >> 3) * 128;
    GEMM_MAINLOOP(Ab, Wt, m0, n0)

    const int ncol0 = n0 + wn * 64;
    float bia[4];
#pragma unroll
    for (int ni = 0; ni < 4; ni++) bia[ni] = bias[ncol0 + ni * 16 + l16];
#pragma unroll
    for (int mi = 0; mi < 4; mi++) {
#pragma unroll
        for (int i = 0; i < 4; i++) {
            int m = m0 + wm * 64 + mi * 16 + quad * 4 + i;
#pragma unroll
            for (int ni = 0; ni < 4; ni++)
                out[(size_t)m * CDIM + ncol0 + ni * 16 + l16] = acc[mi][ni][i] + bia[ni];
        }
    }
}

// ---------------------------------------------------------------------------
extern "C" void kernel_launch(void* const* d_in, const int* in_sizes, int n_in,
                              void* d_out, int out_size, void* d_ws, size_t ws_size,
                              hipStream_t stream)
{
    const float* x    = (const float*)d_in[0];
    const float* Wqkv = (const float*)d_in[1];
    const float* bqkv = (const float*)d_in[2];
    const float* Wout = (const float*)d_in[3];
    const float* bout = (const float*)d_in[4];
    float* out = (float*)d_out;

    const size_t XSZ  = (size_t)MROWS * CDIM;        // 8,388,608
    const size_t WQSZ = (size_t)3072 * CDIM;         // 3,145,728
    const size_t WOSZ = (size_t)CDIM * CDIM;         // 1,048,576
    const size_t QSZ  = (size_t)BHN * T_SEQ * DHD;   // 8,388,608

    char* p = (char*)d_ws;
    f16* Xf  = (f16*)p; p += XSZ * 2;
    f16* Wqt = (f16*)p; p += WQSZ * 2;
    f16* Wot = (f16*)p; p += WOSZ * 2;
    f16* qf  = (f16*)p; p += QSZ * 2;
    f16* kf  = (f16*)p; p += QSZ * 2;
    f16* vtb = (f16*)p; p += QSZ * 2;
    f16* ab  = (f16*)p; p += QSZ * 2;
    float* ctab = (float*)p; p += T_SEQ * 32 * 4;
    float* stab = (float*)p; p += T_SEQ * 32 * 4;
    // total ~94 MB

    prep_kernel<<<6400, 256, 0, stream>>>(x, Xf, Wqkv, Wout, Wqt, Wot, ctab, stab);
    qkv_gemm_kernel<<<dim3(64, 24), 256, 0, stream>>>(
        Xf, Wqt, bqkv, ctab, stab, qf, kf, vtb);
    attn_kernel<<<dim3(16, BHN), 256, 0, stream>>>(qf, kf, vtb, ab);
    out_gemm_kernel<<<dim3(64, 8), 256, 0, stream>>>(ab, Wot, bout, out);
}

// Round 14
// 271.860 us; speedup vs baseline: 1.0390x; 1.0390x over previous
//
#include <hip/hip_runtime.h>
#include <math.h>

// Problem constants
#define T_SEQ 2048
#define CDIM  1024
#define NH    16
#define DHD   64
#define BATCH 4
#define MROWS (BATCH * T_SEQ)   // 8192
#define BHN   (BATCH * NH)      // 64

typedef _Float16 f16;
typedef __attribute__((ext_vector_type(8))) _Float16 f16x8;
typedef __attribute__((ext_vector_type(4))) _Float16 f16x4;
typedef __attribute__((ext_vector_type(2))) _Float16 f16x2;
typedef __attribute__((ext_vector_type(2))) __fp16 fp16x2;
typedef __attribute__((ext_vector_type(4))) float f32x4;
typedef __attribute__((ext_vector_type(16))) float f32x16;
typedef __attribute__((ext_vector_type(4))) unsigned int uint4v;

__device__ __forceinline__ float fast_exp2(float x) {
#if __has_builtin(__builtin_amdgcn_exp2f)
    return __builtin_amdgcn_exp2f(x);
#else
    return exp2f(x);
#endif
}

__device__ __forceinline__ float fast_rcp(float x) {
#if __has_builtin(__builtin_amdgcn_rcpf)
    return __builtin_amdgcn_rcpf(x);
#else
    return 1.0f / x;
#endif
}

// packed f32x2 -> f16x2 convert (v_cvt_pkrtz_f16_f32)
__device__ __forceinline__ f16x2 cvt_pk_f16(float a, float b) {
    fp16x2 r = __builtin_amdgcn_cvt_pkrtz(a, b);
    return __builtin_bit_cast(f16x2, r);
}

// v_permlane32_swap_b32: positional 32-lane half exchange
__device__ __forceinline__ void permlane32_swap(unsigned &a, unsigned &b) {
    asm volatile("v_permlane32_swap_b32 %0, %1" : "+v"(a), "+v"(b));
}

// async global->LDS, 16B per lane; LDS dest = wave-uniform base + lane*16
__device__ __forceinline__ void gl_lds16(const f16* g, f16* l) {
    __builtin_amdgcn_global_load_lds(
        (const __attribute__((address_space(1))) void*)(g),
        (__attribute__((address_space(3))) void*)(l),
        16, 0, 0);
}

// ---------------------------------------------------------------------------
// Prep kernel (one launch): RoPE tables + X fp32->f16 + both W transposes
// ---------------------------------------------------------------------------
__global__ __launch_bounds__(256) void prep_kernel(
    const float* __restrict__ X, f16* __restrict__ Xf,
    const float* __restrict__ Wq, const float* __restrict__ Wo,
    f16* __restrict__ Wqt, f16* __restrict__ Wot,
    float* __restrict__ ctab, float* __restrict__ stab)
{
    const int bx = blockIdx.x;
    if (bx < 256) {
        int idx = bx * 256 + threadIdx.x;   // 0 .. 2048*32-1
        int t = idx >> 5, i = idx & 31;
        double inv = pow(10000.0, -(double)(2 * i) / 64.0);
        double a = (double)t * inv;
        ctab[idx] = (float)cos(a);
        stab[idx] = (float)sin(a);
    } else if (bx < 4352) {
        int idx = (bx - 256) * 256 + threadIdx.x;   // 8-elem chunk index
        const float4* src = (const float4*)X + (size_t)idx * 2;
        float4 a = src[0], b = src[1];
        f16x8 o;
        o[0] = (f16)a.x; o[1] = (f16)a.y; o[2] = (f16)a.z; o[3] = (f16)a.w;
        o[4] = (f16)b.x; o[5] = (f16)b.y; o[6] = (f16)b.z; o[7] = (f16)b.w;
        *((f16x8*)Xf + idx) = o;
    } else {
        const int sub = threadIdx.x >> 6, lane = threadIdx.x & 63;
        const int id = (bx - 4352) * 4 + sub;   // 0..8191
        const int k0 = (id & 127) * 8;
        const int ny = id >> 7;                 // 0..63
        const float* W;
        f16* Wt;
        int N, n;
        if (ny < 48) { W = Wq; Wt = Wqt; N = 3072; n = ny * 64 + lane; }
        else         { W = Wo; Wt = Wot; N = 1024; n = (ny - 48) * 64 + lane; }
        f16x8 o;
#pragma unroll
        for (int j = 0; j < 8; j++) o[j] = (f16)W[(size_t)(k0 + j) * N + n];
        *(f16x8*)(Wt + (size_t)n * CDIM + k0) = o;
    }
}

// ---------------------------------------------------------------------------
// f16 MFMA GEMM mainloop (128x128, 2-barrier, BK=64, XOR-swizzled) —
// the R5-proven structure; used by BOTH qkv and out_gemm.
// ---------------------------------------------------------------------------
#define GEMM_MAINLOOP(Aimg, Bimg, M0, N0)                                         \
    __shared__ f16 As[128][64], Bs[128][64];                                      \
    const int tid = threadIdx.x, wave = tid >> 6, lane = tid & 63;                \
    const int l16 = lane & 15, quad = lane >> 4;                                  \
    const int wm = wave >> 1, wn = wave & 1;                                      \
    f32x4 acc[4][4];                                                              \
    _Pragma("unroll") for (int i = 0; i < 4; i++)                                 \
        _Pragma("unroll") for (int j = 0; j < 4; j++)                             \
            acc[i][j] = (f32x4){0.f, 0.f, 0.f, 0.f};                              \
    const f16* sbase = (wave < 2) ? (Aimg) : (Bimg);                              \
    f16* lbase = ((wave < 2) ? &As[0][0] : &Bs[0][0]) + (wave & 1) * 4096;        \
    const size_t srow0 = ((wave < 2) ? (size_t)(M0) : (size_t)(N0)) + (wave & 1) * 64; \
    const int srow = lane >> 3, schunk = lane & 7;                                \
    const int gchunk = (schunk ^ srow) << 3;   /* pre-swizzled global col */      \
    for (int k0 = 0; k0 < CDIM; k0 += 64) {                                       \
        _Pragma("unroll") for (int it = 0; it < 8; it++)                          \
            gl_lds16(sbase + (srow0 + it * 8 + srow) * CDIM + k0 + gchunk,        \
                     lbase + it * 512);                                           \
        __syncthreads();                                                          \
        _Pragma("unroll") for (int ks = 0; ks < 2; ks++) {                        \
            f16x8 fa[4], fb[4];                                                   \
            _Pragma("unroll") for (int mi = 0; mi < 4; mi++)                      \
                fa[mi] = *(const f16x8*)                                          \
                    &As[wm * 64 + mi * 16 + l16][((ks * 4 + quad) ^ (l16 & 7)) << 3]; \
            _Pragma("unroll") for (int ni = 0; ni < 4; ni++)                      \
                fb[ni] = *(const f16x8*)                                          \
                    &Bs[wn * 64 + ni * 16 + l16][((ks * 4 + quad) ^ (l16 & 7)) << 3]; \
            _Pragma("unroll") for (int mi = 0; mi < 4; mi++)                      \
                _Pragma("unroll") for (int ni = 0; ni < 4; ni++)                  \
                    acc[mi][ni] = __builtin_amdgcn_mfma_f32_16x16x32_f16(         \
                        fa[mi], fb[ni], acc[mi][ni], 0, 0, 0);                    \
        }                                                                         \
        __syncthreads();                                                          \
    }

// ---------------------------------------------------------------------------
// QKV GEMM — R7 configuration (behind all three <=277us totals):
// 128x128 swizzled mainloop, fused bias + RoPE (standard layout), V stored
// directly transposed into vt[bh][d][t].
// Q pre-scaled by (1/8)*log2(e) --> attn uses exp2 directly.
// ---------------------------------------------------------------------------
__global__ __launch_bounds__(256) void qkv_gemm_kernel(
    const f16* __restrict__ Xf, const f16* __restrict__ Wt,
    const float* __restrict__ bias,
    const float* __restrict__ ctab, const float* __restrict__ stab,
    f16* __restrict__ qf, f16* __restrict__ kf, f16* __restrict__ vtb)
{
    const int m0 = blockIdx.x * 128;
    const int n0 = blockIdx.y * 128;
    GEMM_MAINLOOP(Xf, Wt, m0, n0)

    const int ncol0 = n0 + wn * 64;            // 64-aligned -> one head group
    const int w = ncol0 >> 10;                 // 0=q 1=k 2=v
    const int h = (ncol0 >> 6) & 15;
    const int b = m0 >> 11;
    const int trow0 = (m0 & 2047) + wm * 64 + quad * 4;
    float bia[4];
#pragma unroll
    for (int ni = 0; ni < 4; ni++) bia[ni] = bias[ncol0 + ni * 16 + l16];

    if (w < 2) {
        f16* oq = w ? kf : qf;
        // q scale folds softmax 1/8 AND log2(e) so attn can use v_exp (2^x)
        const float sc = w ? 1.0f : 0.18033688011112042f;
#pragma unroll
        for (int mi = 0; mi < 4; mi++) {
#pragma unroll
            for (int i = 0; i < 4; i++) {
                int t = trow0 + mi * 16 + i;
                size_t rowoff = ((size_t)(b * NH + h) * T_SEQ + t) * DHD;
#pragma unroll
                for (int np = 0; np < 2; np++) {
                    int d = np * 16 + l16;             // 0..31
                    float v0 = acc[mi][np][i] + bia[np];
                    float v1 = acc[mi][np + 2][i] + bia[np + 2];
                    float c = ctab[(t << 5) + d];
                    float s = stab[(t << 5) + d];
                    oq[rowoff + d]      = (f16)((v0 * c - v1 * s) * sc);
                    oq[rowoff + d + 32] = (f16)((v1 * c + v0 * s) * sc);
                }
            }
        }
    } else {
        // V: store transposed. acc[mi][ni][0..3] are 4 consecutive t for one
        // d -> one f16x4 store per (mi,ni) into vt[bh][d][t].
#pragma unroll
        for (int mi = 0; mi < 4; mi++) {
            const int tb = trow0 + mi * 16;    // includes quad*4; 4-aligned
#pragma unroll
            for (int ni = 0; ni < 4; ni++) {
                const int d = ni * 16 + l16;
                f16x4 pv;
#pragma unroll
                for (int i = 0; i < 4; i++) pv[i] = (f16)(acc[mi][ni][i] + bia[ni]);
                *(f16x4*)(vtb + ((size_t)(b * NH + h) * DHD + d) * T_SEQ + tb) = pv;
            }
        }
    }
}

// ---------------------------------------------------------------------------
// f16 MFMA flash attention — R12 configuration (best measured: 83.0us):
//  - 128-query blocks, 4 waves x 32 q; grid 16x64 = 1024 blocks = 4/CU
//  - 32x32 MFMA S^T (A=K, B=Q); register-only P via permlane32_swap
//  - serial per-lane l accumulation (beats MFMA-l by 2.7us: the VALU chain
//    hides under MFMA latency; extra l-MFMAs don't)
//  - zero16 as C-input of first QK^T MFMA; incremental staging pointers
//  - gl_lds staging w/ pre-swizzled global source; XCD-chunked block swizzle
// ---------------------------------------------------------------------------
__global__ __launch_bounds__(256, 4) void attn_kernel(
    const f16* __restrict__ qf, const f16* __restrict__ kf,
    const f16* __restrict__ vt, f16* __restrict__ ab)
{
    __shared__ f16 Kb[2][64][64];     // [buf][key][d]   16384B, chunk-swizzled
    __shared__ f16 Vb[2][64][64];     // [buf][d][key]   16384B, chunk-swizzled
    __shared__ float Lb[4][32];       // per-wave l per query, 512B

    const int tid  = threadIdx.x;
    const int wave = tid >> 6, lane = tid & 63;
    const int l31  = lane & 31, hh = lane >> 5;

    // XCD-chunked swizzle: flat id -> (qt, bh) so XCD x holds bh in [8x, 8x+8)
    const int flat = blockIdx.x + (blockIdx.y << 4);     // 0..1023
    const int swz  = (flat & 7) * 128 + (flat >> 3);     // bijective (1024%8==0)
    const int qt = swz & 15;                             // 0..15
    const int bh = swz >> 4;                             // 0..63
    const int q0 = qt * 128 + wave * 32;                 // wave's query base

    const f16* kbase = kf + (size_t)bh * T_SEQ * DHD;
    const f16* vbase = vt + (size_t)bh * DHD * T_SEQ;

    // Q B-frags: qfr[kk] = Q[query=q0+l31][d = kk*16 + hh*8 .. +7]
    f16x8 qfr[4];
    {
        const f16* qrow = qf + ((size_t)bh * T_SEQ + q0 + l31) * DHD + hh * 8;
#pragma unroll
        for (int kk = 0; kk < 4; kk++)
            qfr[kk] = *(const f16x8*)(qrow + kk * 16);
    }

    f32x16 o[2];        // [dblk]: C row=query=(r&3)+8*(r>>2)+4*hh, col=d=dblk*32+l31
#pragma unroll
    for (int db = 0; db < 2; db++)
#pragma unroll
        for (int r = 0; r < 16; r++) o[db][r] = 0.f;
    float lacc = 0.f;

    // never-modified zero accumulator: C-input of the first QK^T MFMA
    f32x16 zero16;
#pragma unroll
    for (int r = 0; r < 16; r++) zero16[r] = 0.f;

    // staging map (gl_lds): thread -> row srow(+32), phys chunk schunk;
    // global col pre-XORed so phys chunk p of row r = global chunk p^(r&7)
    const int srow = tid >> 3;                       // 0..31
    const int schunk = tid & 7;
    const int gcol = (schunk ^ (srow & 7)) << 3;

    // incremental per-lane staging pointers
    const f16* kg = kbase + (size_t)srow * DHD + gcol;
    const f16* vg = vbase + (size_t)srow * T_SEQ + gcol;

    {   // stage tile 0 into buf 0
        f16* kl = &Kb[0][wave * 8][0];
        f16* vl = &Vb[0][wave * 8][0];
        gl_lds16(kg, kl);
        gl_lds16(kg + 32 * DHD, kl + 32 * 64);
        gl_lds16(vg, vl);
        gl_lds16(vg + (size_t)32 * T_SEQ, vl + 32 * 64);
        kg += 64 * DHD;
        vg += 64;
    }
    __syncthreads();

    for (int kt = 0; kt < 32; kt++) {
        const int buf = kt & 1;
        if (kt < 31) {   // stage next tile into the other buffer
            f16* kl = &Kb[buf ^ 1][wave * 8][0];
            f16* vl = &Vb[buf ^ 1][wave * 8][0];
            gl_lds16(kg, kl);
            gl_lds16(kg + 32 * DHD, kl + 32 * 64);
            gl_lds16(vg, vl);
            gl_lds16(vg + (size_t)32 * T_SEQ, vl + 32 * 64);
            kg += 64 * DHD;
            vg += 64;
        }

        f16x8 pA[4];    // PV A-frags, keys kk*16 + hh*8 + j of query l31
#pragma unroll
        for (int b2 = 0; b2 < 2; b2++) {
            // ---- S^T for 32-key block b2 x 32 queries ----
            f32x16 scc;
            __builtin_amdgcn_s_setprio(1);
#pragma unroll
            for (int kk = 0; kk < 4; kk++) {
                const int kc = ((kk * 2 + hh) ^ (l31 & 7)) << 3;
                f16x8 kfr = *(const f16x8*)&Kb[buf][b2 * 32 + l31][kc];
                scc = __builtin_amdgcn_mfma_f32_32x32x16_f16(
                    kfr, qfr[kk], kk == 0 ? zero16 : scc, 0, 0, 0);
            }
            __builtin_amdgcn_s_setprio(0);
            // ---- exp2 + per-lane l partial + pack ----
            float e[16];
#pragma unroll
            for (int r = 0; r < 16; r++) {
                e[r] = fast_exp2(scc[r]);
                lacc += e[r];
            }
            unsigned pk[8];
#pragma unroll
            for (int i = 0; i < 8; i++)
                pk[i] = __builtin_bit_cast(unsigned,
                                           cvt_pk_f16(e[2 * i], e[2 * i + 1]));
            // ---- half-exchange: pk -> A-frag dwords ----
            permlane32_swap(pk[0], pk[2]);
            permlane32_swap(pk[1], pk[3]);
            permlane32_swap(pk[4], pk[6]);
            permlane32_swap(pk[5], pk[7]);
            uint4v a0 = {pk[0], pk[1], pk[2], pk[3]};
            uint4v a1 = {pk[4], pk[5], pk[6], pk[7]};
            pA[b2 * 2]     = __builtin_bit_cast(f16x8, a0);
            pA[b2 * 2 + 1] = __builtin_bit_cast(f16x8, a1);
        }
        // ---- PV: o[dblk] += P * V ----
        __builtin_amdgcn_s_setprio(1);
#pragma unroll
        for (int db = 0; db < 2; db++) {
#pragma unroll
            for (int kk = 0; kk < 4; kk++) {
                const int vc = ((kk * 2 + hh) ^ (l31 & 7)) << 3;
                f16x8 vfr = *(const f16x8*)&Vb[buf][db * 32 + l31][vc];
                o[db] = __builtin_amdgcn_mfma_f32_32x32x16_f16(
                    pA[kk], vfr, o[db], 0, 0, 0);
            }
        }
        __builtin_amdgcn_s_setprio(0);

        if (kt < 31) __syncthreads();
    }

    // ---- l: total over both halves; redistribute per-query via Lb ----
    lacc += __shfl_xor(lacc, 32);
    if (lane < 32) Lb[wave][l31] = lacc;
    __syncthreads();
    f32x4 ivv[4];
#pragma unroll
    for (int g = 0; g < 4; g++)
        ivv[g] = *(const f32x4*)&Lb[wave][g * 8 + hh * 4];

    // ---- epilogue: normalize, write ab[m][h*64 + d] ----
    const int b = bh >> 4, h = bh & 15;
#pragma unroll
    for (int r = 0; r < 16; r++) {
        const int qrow = (r & 3) + 8 * (r >> 2) + 4 * hh;
        const int m = b * T_SEQ + qt * 128 + wave * 32 + qrow;
        const float iv = fast_rcp(ivv[r >> 2][r & 3]);
        f16* dst = ab + (size_t)m * CDIM + h * 64 + l31;
        dst[0]  = (f16)(o[0][r] * iv);
        dst[32] = (f16)(o[1][r] * iv);
    }
}

// ---------------------------------------------------------------------------
// Output GEMM (f16 MFMA): out = ab @ Wout + bias (fp32 out)
// ---------------------------------------------------------------------------
__global__ __launch_bounds__(256) void out_gemm_kernel(
    const f16* __restrict__ Ab, const f16* __restrict__ Wt,
    const float* __restrict__ bias, float* __restrict__ out)
{
    const int m0 = blockIdx.x * 128;
    const int n0 = blockIdx.y * 128;
    GEMM_MAINLOOP(Ab, Wt, m0, n0)

    const int ncol0 = n0 + wn * 64;
    float bia[4];
#pragma unroll
    for (int ni = 0; ni < 4; ni++) bia[ni] = bias[ncol0 + ni * 16 + l16];
#pragma unroll
    for (int mi = 0; mi < 4; mi++) {
#pragma unroll
        for (int i = 0; i < 4; i++) {
            int m = m0 + wm * 64 + mi * 16 + quad * 4 + i;
#pragma unroll
            for (int ni = 0; ni < 4; ni++)
                out[(size_t)m * CDIM + ncol0 + ni * 16 + l16] = acc[mi][ni][i] + bia[ni];
        }
    }
}

// ---------------------------------------------------------------------------
extern "C" void kernel_launch(void* const* d_in, const int* in_sizes, int n_in,
                              void* d_out, int out_size, void* d_ws, size_t ws_size,
                              hipStream_t stream)
{
    const float* x    = (const float*)d_in[0];
    const float* Wqkv = (const float*)d_in[1];
    const float* bqkv = (const float*)d_in[2];
    const float* Wout = (const float*)d_in[3];
    const float* bout = (const float*)d_in[4];
    float* out = (float*)d_out;

    const size_t XSZ  = (size_t)MROWS * CDIM;        // 8,388,608
    const size_t WQSZ = (size_t)3072 * CDIM;         // 3,145,728
    const size_t WOSZ = (size_t)CDIM * CDIM;         // 1,048,576
    const size_t QSZ  = (size_t)BHN * T_SEQ * DHD;   // 8,388,608

    char* p = (char*)d_ws;
    f16* Xf  = (f16*)p; p += XSZ * 2;
    f16* Wqt = (f16*)p; p += WQSZ * 2;
    f16* Wot = (f16*)p; p += WOSZ * 2;
    f16* qf  = (f16*)p; p += QSZ * 2;
    f16* kf  = (f16*)p; p += QSZ * 2;
    f16* vtb = (f16*)p; p += QSZ * 2;
    f16* ab  = (f16*)p; p += QSZ * 2;
    float* ctab = (float*)p; p += T_SEQ * 32 * 4;
    float* stab = (float*)p; p += T_SEQ * 32 * 4;
    // total ~94 MB

    prep_kernel<<<6400, 256, 0, stream>>>(x, Xf, Wqkv, Wout, Wqt, Wot, ctab, stab);
    qkv_gemm_kernel<<<dim3(64, 24), 256, 0, stream>>>(
        Xf, Wqt, bqkv, ctab, stab, qf, kf, vtb);
    attn_kernel<<<dim3(16, BHN), 256, 0, stream>>>(qf, kf, vtb, ab);
    out_gemm_kernel<<<dim3(64, 8), 256, 0, stream>>>(ab, Wot, bout, out);
}